// Round 4
// baseline (317.509 us; speedup 1.0000x reference)
//
#include <hip/hip_runtime.h>

// PiecewiseSparseMLP: B=262144 rows, K=32 experts (10 -> 20 -> 1), distance-softmax gating.
// Round 4: 2 rows per thread to halve LDS broadcast-read pressure per row (R3 was
// LDS-issue-bound: ~64 ds_read_b128/expert/wave with zero per-thread reuse).
// Block=512, 4-way expert split, 256 rows/block, grid=1024 = one full residency round.

#define KX 32
#define DIN 10
#define DH 20
#define HALF_RPB 128
#define RPB 256
#define BLOCK 512

typedef float v2f __attribute__((ext_vector_type(2)));

__global__ __launch_bounds__(BLOCK, 8) void moe_kernel(
    const float* __restrict__ x,      // [B,10]
    const float* __restrict__ W1,     // [32,20,10] = [k][200] contiguous
    const float* __restrict__ b1,     // [32,20]
    const float* __restrict__ W2,     // [32,1,20]
    const float* __restrict__ b2,     // [32]
    const float* __restrict__ proto,  // [32,10]
    float* __restrict__ out,          // [B]
    int B)
{
    __shared__ float4 s_w1[KX * 50];      // W1 verbatim
    __shared__ float4 s_bw[KX * 10];      // {b1[j], w2[j]} interleaved
    __shared__ float4 s_pr[KX * 3];       // proto padded 10->12
    __shared__ float  s_b2[KX];
    __shared__ float4 s_red[3 * HALF_RPB]; // {num0,den0,num1,den1} per group

    const int tid = threadIdx.x;

    // ---- stage weights to LDS (one-time, coalesced) ----
    {
        const float4* gW1 = (const float4*)W1;
        for (int t = tid; t < KX * 50; t += BLOCK) s_w1[t] = gW1[t];
        float2* bw = (float2*)s_bw;
        for (int t = tid; t < KX * DH; t += BLOCK) bw[t] = make_float2(b1[t], W2[t]);
        float* pr = (float*)s_pr;
        for (int t = tid; t < KX * DIN; t += BLOCK) {
            const int row = t / DIN;
            pr[row * 12 + (t - row * DIN)] = proto[t];
        }
        if (tid < KX) s_b2[tid] = b2[tid];
    }

    const int rl = tid & (HALF_RPB - 1);
    // wave-uniform expert-group selector (waves 2g,2g+1 -> group g)
    const int g = __builtin_amdgcn_readfirstlane(tid >> 7);
    const int k0 = g * (KX / 4);

    const int r0 = blockIdx.x * RPB + rl;
    const int r1 = r0 + HALF_RPB;
    const int rr0 = (r0 < B) ? r0 : (B - 1);
    const int rr1 = (r1 < B) ? r1 : (B - 1);

    v2f xa[5], xb[5];
    {
        const float2* gx = (const float2*)(x + (size_t)rr0 * DIN);
#pragma unroll
        for (int i = 0; i < 5; ++i) { float2 t = gx[i]; xa[i] = v2f{t.x, t.y}; }
    }
    {
        const float2* gx = (const float2*)(x + (size_t)rr1 * DIN);
#pragma unroll
        for (int i = 0; i < 5; ++i) { float2 t = gx[i]; xb[i] = v2f{t.x, t.y}; }
    }

    __syncthreads();

    float num0 = 0.f, den0 = 0.f, num1 = 0.f, den1 = 0.f;

#pragma unroll 1
    for (int kk = 0; kk < KX / 4; ++kk) {
        const int k = k0 + kk;

        // ---- gating for both rows ----
        const float4 p0 = s_pr[k * 3 + 0];
        const float4 p1 = s_pr[k * 3 + 1];
        const float4 p2 = s_pr[k * 3 + 2];
        const v2f pv0 = v2f{p0.x, p0.y}, pv1 = v2f{p0.z, p0.w},
                  pv2 = v2f{p1.x, p1.y}, pv3 = v2f{p1.z, p1.w},
                  pv4 = v2f{p2.x, p2.y};
        v2f dA = v2f{0.f, 0.f}, dB = v2f{0.f, 0.f};
        {
            v2f d;
            d = xa[0] - pv0; dA = __builtin_elementwise_fma(d, d, dA);
            d = xa[1] - pv1; dA = __builtin_elementwise_fma(d, d, dA);
            d = xa[2] - pv2; dA = __builtin_elementwise_fma(d, d, dA);
            d = xa[3] - pv3; dA = __builtin_elementwise_fma(d, d, dA);
            d = xa[4] - pv4; dA = __builtin_elementwise_fma(d, d, dA);
            d = xb[0] - pv0; dB = __builtin_elementwise_fma(d, d, dB);
            d = xb[1] - pv1; dB = __builtin_elementwise_fma(d, d, dB);
            d = xb[2] - pv2; dB = __builtin_elementwise_fma(d, d, dB);
            d = xb[3] - pv3; dB = __builtin_elementwise_fma(d, d, dB);
            d = xb[4] - pv4; dB = __builtin_elementwise_fma(d, d, dB);
        }
        const float gate0 = __expf(-__fsqrt_rn(dA.x + dA.y));
        const float gate1 = __expf(-__fsqrt_rn(dB.x + dB.y));

        // ---- expert MLP, hidden pairs: 5 W1 f4 reads serve BOTH rows ----
        float pred0 = s_b2[k];
        float pred1 = pred0;
        const float4* wk = &s_w1[k * 50];
        const float4* bwk = &s_bw[k * 10];
#pragma unroll
        for (int j2 = 0; j2 < DH / 2; ++j2) {
            const float4 A  = wk[j2 * 5 + 0];
            const float4 Bq = wk[j2 * 5 + 1];
            const float4 C  = wk[j2 * 5 + 2];
            const float4 D  = wk[j2 * 5 + 3];
            const float4 E  = wk[j2 * 5 + 4];
            const v2f w0 = v2f{A.x, A.y},  w1v = v2f{A.z, A.w},
                      w2v = v2f{Bq.x, Bq.y}, w3 = v2f{Bq.z, Bq.w},
                      w4 = v2f{C.x, C.y};
            const v2f u0 = v2f{C.z, C.w}, u1 = v2f{D.x, D.y},
                      u2 = v2f{D.z, D.w}, u3 = v2f{E.x, E.y},
                      u4 = v2f{E.z, E.w};

            v2f a0 = v2f{0.f, 0.f}, a1 = v2f{0.f, 0.f};
            v2f c0 = v2f{0.f, 0.f}, c1 = v2f{0.f, 0.f};
            a0 = __builtin_elementwise_fma(w0,  xa[0], a0);
            c0 = __builtin_elementwise_fma(w0,  xb[0], c0);
            a0 = __builtin_elementwise_fma(w1v, xa[1], a0);
            c0 = __builtin_elementwise_fma(w1v, xb[1], c0);
            a0 = __builtin_elementwise_fma(w2v, xa[2], a0);
            c0 = __builtin_elementwise_fma(w2v, xb[2], c0);
            a0 = __builtin_elementwise_fma(w3,  xa[3], a0);
            c0 = __builtin_elementwise_fma(w3,  xb[3], c0);
            a0 = __builtin_elementwise_fma(w4,  xa[4], a0);
            c0 = __builtin_elementwise_fma(w4,  xb[4], c0);
            a1 = __builtin_elementwise_fma(u0,  xa[0], a1);
            c1 = __builtin_elementwise_fma(u0,  xb[0], c1);
            a1 = __builtin_elementwise_fma(u1,  xa[1], a1);
            c1 = __builtin_elementwise_fma(u1,  xb[1], c1);
            a1 = __builtin_elementwise_fma(u2,  xa[2], a1);
            c1 = __builtin_elementwise_fma(u2,  xb[2], c1);
            a1 = __builtin_elementwise_fma(u3,  xa[3], a1);
            c1 = __builtin_elementwise_fma(u3,  xb[3], c1);
            a1 = __builtin_elementwise_fma(u4,  xa[4], a1);
            c1 = __builtin_elementwise_fma(u4,  xb[4], c1);

            const float4 bwv = bwk[j2];  // {b1[2j2], w2[2j2], b1[2j2+1], w2[2j2+1]}
            float h;
            h = a0.x + a0.y + bwv.x; h = fmaxf(h, 0.f); pred0 = fmaf(bwv.y, h, pred0);
            h = a1.x + a1.y + bwv.z; h = fmaxf(h, 0.f); pred0 = fmaf(bwv.w, h, pred0);
            h = c0.x + c0.y + bwv.x; h = fmaxf(h, 0.f); pred1 = fmaf(bwv.y, h, pred1);
            h = c1.x + c1.y + bwv.z; h = fmaxf(h, 0.f); pred1 = fmaf(bwv.w, h, pred1);
        }

        num0 = fmaf(pred0, gate0, num0);
        den0 += gate0;
        num1 = fmaf(pred1, gate1, num1);
        den1 += gate1;
    }

    // ---- cross-group reduction ----
    if (g) s_red[(g - 1) * HALF_RPB + rl] = make_float4(num0, den0, num1, den1);
    __syncthreads();
    if (g == 0) {
#pragma unroll
        for (int p = 0; p < 3; ++p) {
            const float4 t = s_red[p * HALF_RPB + rl];
            num0 += t.x; den0 += t.y;
            num1 += t.z; den1 += t.w;
        }
        if (r0 < B) out[r0] = num0 / den0;
        if (r1 < B) out[r1] = num1 / den1;
    }
}

extern "C" void kernel_launch(void* const* d_in, const int* in_sizes, int n_in,
                              void* d_out, int out_size, void* d_ws, size_t ws_size,
                              hipStream_t stream) {
    const float* x     = (const float*)d_in[0];
    const float* W1    = (const float*)d_in[1];
    const float* b1    = (const float*)d_in[2];
    const float* W2    = (const float*)d_in[3];
    const float* b2    = (const float*)d_in[4];
    const float* proto = (const float*)d_in[5];
    float* out = (float*)d_out;

    const int B = out_size;  // D_OUT = 1
    const int grid = (B + RPB - 1) / RPB;
    hipLaunchKernelGGL(moe_kernel, dim3(grid), dim3(BLOCK), 0, stream,
                       x, W1, b1, W2, b2, proto, out, B);
}

// Round 5
// 119.467 us; speedup vs baseline: 2.6577x; 2.6577x over previous
//
#include <hip/hip_runtime.h>

// PiecewiseSparseMLP: B=262144 rows, K=32 experts (10 -> 20 -> 1), distance-softmax gating.
// Round 5: R4's 2-rows-per-thread (halves LDS broadcast pressure) with the register
// cap RELAXED: __launch_bounds__(512,6) -> ~80 VGPR budget, 24 waves/CU. R4's (512,8)
// 64-VGPR cap caused a catastrophic scratch-spill storm (762 MB WRITE_SIZE).
// Weight float4s staged in two chunks + unroll 2 to keep live pressure ~70 regs.

#define KX 32
#define DIN 10
#define DH 20
#define HALF_RPB 128
#define RPB 256
#define BLOCK 512

typedef float v2f __attribute__((ext_vector_type(2)));

__global__ __launch_bounds__(BLOCK, 6) void moe_kernel(
    const float* __restrict__ x,      // [B,10]
    const float* __restrict__ W1,     // [32,20,10] = [k][200] contiguous
    const float* __restrict__ b1,     // [32,20]
    const float* __restrict__ W2,     // [32,1,20]
    const float* __restrict__ b2,     // [32]
    const float* __restrict__ proto,  // [32,10]
    float* __restrict__ out,          // [B]
    int B)
{
    __shared__ float4 s_w1[KX * 50];      // W1 verbatim
    __shared__ float4 s_bw[KX * 10];      // {b1[j], w2[j]} interleaved
    __shared__ float4 s_pr[KX * 3];       // proto padded 10->12
    __shared__ float  s_b2[KX];
    __shared__ float4 s_red[3 * HALF_RPB]; // {num0,den0,num1,den1} per group

    const int tid = threadIdx.x;

    // ---- stage weights to LDS (one-time, coalesced) ----
    {
        const float4* gW1 = (const float4*)W1;
        for (int t = tid; t < KX * 50; t += BLOCK) s_w1[t] = gW1[t];
        float2* bw = (float2*)s_bw;
        for (int t = tid; t < KX * DH; t += BLOCK) bw[t] = make_float2(b1[t], W2[t]);
        float* pr = (float*)s_pr;
        for (int t = tid; t < KX * DIN; t += BLOCK) {
            const int row = t / DIN;
            pr[row * 12 + (t - row * DIN)] = proto[t];
        }
        if (tid < KX) s_b2[tid] = b2[tid];
    }

    const int rl = tid & (HALF_RPB - 1);
    // wave-uniform expert-group selector (waves 2g,2g+1 -> group g)
    const int g = __builtin_amdgcn_readfirstlane(tid >> 7);
    const int k0 = g * (KX / 4);

    const int r0 = blockIdx.x * RPB + rl;
    const int r1 = r0 + HALF_RPB;
    const int rr0 = (r0 < B) ? r0 : (B - 1);
    const int rr1 = (r1 < B) ? r1 : (B - 1);

    v2f xa[5], xb[5];
    {
        const float2* gx = (const float2*)(x + (size_t)rr0 * DIN);
#pragma unroll
        for (int i = 0; i < 5; ++i) { float2 t = gx[i]; xa[i] = v2f{t.x, t.y}; }
    }
    {
        const float2* gx = (const float2*)(x + (size_t)rr1 * DIN);
#pragma unroll
        for (int i = 0; i < 5; ++i) { float2 t = gx[i]; xb[i] = v2f{t.x, t.y}; }
    }

    __syncthreads();

    float num0 = 0.f, den0 = 0.f, num1 = 0.f, den1 = 0.f;

#pragma unroll 1
    for (int kk = 0; kk < KX / 4; ++kk) {
        const int k = k0 + kk;

        // ---- gating for both rows ----
        const float4 p0 = s_pr[k * 3 + 0];
        const float4 p1 = s_pr[k * 3 + 1];
        const float4 p2 = s_pr[k * 3 + 2];
        v2f dA = v2f{0.f, 0.f}, dB = v2f{0.f, 0.f};
        {
            v2f d;
            d = xa[0] - v2f{p0.x, p0.y}; dA = __builtin_elementwise_fma(d, d, dA);
            d = xb[0] - v2f{p0.x, p0.y}; dB = __builtin_elementwise_fma(d, d, dB);
            d = xa[1] - v2f{p0.z, p0.w}; dA = __builtin_elementwise_fma(d, d, dA);
            d = xb[1] - v2f{p0.z, p0.w}; dB = __builtin_elementwise_fma(d, d, dB);
            d = xa[2] - v2f{p1.x, p1.y}; dA = __builtin_elementwise_fma(d, d, dA);
            d = xb[2] - v2f{p1.x, p1.y}; dB = __builtin_elementwise_fma(d, d, dB);
            d = xa[3] - v2f{p1.z, p1.w}; dA = __builtin_elementwise_fma(d, d, dA);
            d = xb[3] - v2f{p1.z, p1.w}; dB = __builtin_elementwise_fma(d, d, dB);
            d = xa[4] - v2f{p2.x, p2.y}; dA = __builtin_elementwise_fma(d, d, dA);
            d = xb[4] - v2f{p2.x, p2.y}; dB = __builtin_elementwise_fma(d, d, dB);
        }
        const float gate0 = __expf(-__fsqrt_rn(dA.x + dA.y));
        const float gate1 = __expf(-__fsqrt_rn(dB.x + dB.y));

        // ---- expert MLP, hidden pairs: 5 W1 f4 reads serve BOTH rows ----
        float pred0 = s_b2[k];
        float pred1 = pred0;
        const float4* wk = &s_w1[k * 50];
        const float4* bwk = &s_bw[k * 10];
#pragma unroll 2
        for (int j2 = 0; j2 < DH / 2; ++j2) {
            // chunk 1: first hidden unit of the pair (weights A,Bq,C.xy)
            const float4 A  = wk[j2 * 5 + 0];
            const float4 Bq = wk[j2 * 5 + 1];
            const float4 C  = wk[j2 * 5 + 2];
            v2f a0 = v2f{0.f, 0.f}, c0 = v2f{0.f, 0.f};
            a0 = __builtin_elementwise_fma(v2f{A.x, A.y},   xa[0], a0);
            c0 = __builtin_elementwise_fma(v2f{A.x, A.y},   xb[0], c0);
            a0 = __builtin_elementwise_fma(v2f{A.z, A.w},   xa[1], a0);
            c0 = __builtin_elementwise_fma(v2f{A.z, A.w},   xb[1], c0);
            a0 = __builtin_elementwise_fma(v2f{Bq.x, Bq.y}, xa[2], a0);
            c0 = __builtin_elementwise_fma(v2f{Bq.x, Bq.y}, xb[2], c0);
            a0 = __builtin_elementwise_fma(v2f{Bq.z, Bq.w}, xa[3], a0);
            c0 = __builtin_elementwise_fma(v2f{Bq.z, Bq.w}, xb[3], c0);
            a0 = __builtin_elementwise_fma(v2f{C.x, C.y},   xa[4], a0);
            c0 = __builtin_elementwise_fma(v2f{C.x, C.y},   xb[4], c0);

            // chunk 2: second hidden unit (weights C.zw, D, E)
            const float4 D  = wk[j2 * 5 + 3];
            const float4 E  = wk[j2 * 5 + 4];
            v2f a1 = v2f{0.f, 0.f}, c1 = v2f{0.f, 0.f};
            a1 = __builtin_elementwise_fma(v2f{C.z, C.w}, xa[0], a1);
            c1 = __builtin_elementwise_fma(v2f{C.z, C.w}, xb[0], c1);
            a1 = __builtin_elementwise_fma(v2f{D.x, D.y}, xa[1], a1);
            c1 = __builtin_elementwise_fma(v2f{D.x, D.y}, xb[1], c1);
            a1 = __builtin_elementwise_fma(v2f{D.z, D.w}, xa[2], a1);
            c1 = __builtin_elementwise_fma(v2f{D.z, D.w}, xb[2], c1);
            a1 = __builtin_elementwise_fma(v2f{E.x, E.y}, xa[3], a1);
            c1 = __builtin_elementwise_fma(v2f{E.x, E.y}, xb[3], c1);
            a1 = __builtin_elementwise_fma(v2f{E.z, E.w}, xa[4], a1);
            c1 = __builtin_elementwise_fma(v2f{E.z, E.w}, xb[4], c1);

            const float4 bwv = bwk[j2];  // {b1[2j2], w2[2j2], b1[2j2+1], w2[2j2+1]}
            float h;
            h = a0.x + a0.y + bwv.x; h = fmaxf(h, 0.f); pred0 = fmaf(bwv.y, h, pred0);
            h = a1.x + a1.y + bwv.z; h = fmaxf(h, 0.f); pred0 = fmaf(bwv.w, h, pred0);
            h = c0.x + c0.y + bwv.x; h = fmaxf(h, 0.f); pred1 = fmaf(bwv.y, h, pred1);
            h = c1.x + c1.y + bwv.z; h = fmaxf(h, 0.f); pred1 = fmaf(bwv.w, h, pred1);
        }

        num0 = fmaf(pred0, gate0, num0);
        den0 += gate0;
        num1 = fmaf(pred1, gate1, num1);
        den1 += gate1;
    }

    // ---- cross-group reduction ----
    if (g) s_red[(g - 1) * HALF_RPB + rl] = make_float4(num0, den0, num1, den1);
    __syncthreads();
    if (g == 0) {
#pragma unroll
        for (int p = 0; p < 3; ++p) {
            const float4 t = s_red[p * HALF_RPB + rl];
            num0 += t.x; den0 += t.y;
            num1 += t.z; den1 += t.w;
        }
        if (r0 < B) out[r0] = num0 / den0;
        if (r1 < B) out[r1] = num1 / den1;
    }
}

extern "C" void kernel_launch(void* const* d_in, const int* in_sizes, int n_in,
                              void* d_out, int out_size, void* d_ws, size_t ws_size,
                              hipStream_t stream) {
    const float* x     = (const float*)d_in[0];
    const float* W1    = (const float*)d_in[1];
    const float* b1    = (const float*)d_in[2];
    const float* W2    = (const float*)d_in[3];
    const float* b2    = (const float*)d_in[4];
    const float* proto = (const float*)d_in[5];
    float* out = (float*)d_out;

    const int B = out_size;  // D_OUT = 1
    const int grid = (B + RPB - 1) / RPB;
    hipLaunchKernelGGL(moe_kernel, dim3(grid), dim3(BLOCK), 0, stream,
                       x, W1, b1, W2, b2, proto, out, B);
}